// Round 4
// baseline (740.628 us; speedup 1.0000x reference)
//
#include <hip/hip_runtime.h>

// PPNet forward, round 6: r0's proven 3-phase structure at TM=32 for occupancy.
// Evidence ledger:
//  - r0 (TM=64, 256t, 3 phases): 117us, VGPR 124, no spill, 2 blocks/CU (LDS 64KB).
//  - r1/r3: allocator won't exceed ~128 VGPR here; structures needing ~200 spill
//    (FETCH/WRITE inflate by the spill round-trip). Merged dual-acc loop: dead end.
//  - r2: 512-thread blocks only ever achieve 1 block/CU -> no TLP from bigger blocks.
// => Occupancy must come from more 256t blocks: TM=32 halves LDS (layer0 fused
//    64->32KB, stats 32->16KB) -> LDS admits 5 blocks/CU; VGPR demand ~110 < 128
//    -> 4-5 blocks/CU resident = 16-20 waves/CU (vs 8). Same per-output math as
//    r0 (absmax-identical); per-wave RT=2, pure N-split, no B duplication.
// fin_k stays inlined in the fused epilogue; gate computed inline from acc2.

typedef __attribute__((ext_vector_type(8))) short short8;
typedef __attribute__((ext_vector_type(4))) float floatx4;

#define BATCH 32768
#define NDOM 4
#define TM 32

__device__ __forceinline__ unsigned short f2b(float f) {
    unsigned u = __float_as_uint(f);
    u += 0x7fffu + ((u >> 16) & 1u);  // round-to-nearest-even
    return (unsigned short)(u >> 16);
}
__device__ __forceinline__ float b2f(unsigned short h) {
    return __uint_as_float(((unsigned)h) << 16);
}

// ---------------------------------------------------------------------------
// Weight prep: fp32 (D,K,N) -> bf16 (D,N,K) packed; zero stat accumulators.
struct MatDesc { const float* src; unsigned K, N, pfx, total; };
struct PrepArgs { MatDesc m[9]; float* stats; unsigned statsN; unsigned grand; };

__global__ __launch_bounds__(256) void prep_k(PrepArgs a, unsigned short* __restrict__ wt) {
    unsigned e = blockIdx.x * 256 + threadIdx.x;
    if (e < a.statsN) a.stats[e] = 0.f;
    if (e >= a.grand) return;
    int j = 0;
    while (j < 8 && e >= a.m[j].pfx + a.m[j].total) j++;
    const unsigned K = a.m[j].K, N = a.m[j].N;
    const unsigned local = e - a.m[j].pfx;
    const unsigned kn = K * N;
    const unsigned d = local / kn;
    const unsigned r2 = local - d * kn;
    const unsigned n = r2 / K;
    const unsigned k = r2 - n * K;
    wt[e] = f2b(a.m[j].src[((long long)d * K + k) * N + n]);
}

// ---------------------------------------------------------------------------
__global__ __launch_bounds__(256) void embed_k(const int* __restrict__ idi, const int* __restrict__ agi,
                                               const float* __restrict__ idt, const float* __restrict__ agt,
                                               unsigned short* __restrict__ gin) {
    int t = blockIdx.x * 256 + threadIdx.x;  // B*16 threads, one per (b, 16-elem slot)
    int b = t >> 4, slot = t & 15;
    int f = slot & 7;
    const int* ip = (slot < 8) ? idi : agi;
    const float* tab = (slot < 8) ? idt : agt;
    int ix = ip[b * 8 + f];
    const float* src = tab + ((long long)f * 100000 + ix) * 16;
    unsigned short tmp[16];
#pragma unroll
    for (int j = 0; j < 16; j++) tmp[j] = f2b(src[j]);
    unsigned short* dst = gin + (long long)b * 256 + slot * 16;
    *(uint4*)dst = *(const uint4*)tmp;
    *(uint4*)(dst + 8) = *(const uint4*)(tmp + 8);
}

// ---------------------------------------------------------------------------
// Stats-only GEMM: acc = X@Wm (no bias), accumulate per-(d,n) sum & sumsq.
// 256 threads, 4 waves pure N-split, TM=32 (RT=2). LDS 16KB (KX=256).
template <int N, int KX>
__global__ __launch_bounds__(256, 2) void stats_k(
    const unsigned short* __restrict__ X, int ginMode,
    const unsigned short* __restrict__ Wm,
    float* __restrict__ gsum, float* __restrict__ gssq) {
    constexpr int GX = KX / 8;
    constexpr int NW = N / 4, CT = NW / 16;
    __shared__ __align__(16) unsigned short tA[TM * KX];
    const int t = threadIdx.x;
    const int d = blockIdx.y;
    const int m0 = blockIdx.x * TM;
    const unsigned short* Xp = X + ((long long)(ginMode ? 0 : d * BATCH) + m0) * KX;
#pragma unroll
    for (int r = 0; r < TM * GX / 256; r++) {
        int idx = r * 256 + t;
        int m = idx / GX, j = idx % GX;
        uint4 v = *(const uint4*)(Xp + (long long)m * KX + j * 8);
        *(uint4*)&tA[(m * GX + (j ^ (m & 7))) * 8] = v;
    }
    __syncthreads();
    const int w = t >> 6, lane = t & 63, lrow = lane & 15, lq = lane >> 4;
    const int n0w = w * NW;
    const unsigned short* Wp = Wm + ((long long)d * N + n0w) * KX;
    floatx4 acc[2][CT];
#pragma unroll
    for (int rt = 0; rt < 2; rt++)
#pragma unroll
        for (int ct = 0; ct < CT; ct++) acc[rt][ct] = (floatx4)(0.f);
#pragma unroll
    for (int k0 = 0; k0 < KX; k0 += 32) {
        short8 a[2], b[CT];
#pragma unroll
        for (int rt = 0; rt < 2; rt++) {
            int m = rt * 16 + lrow;
            a[rt] = *(const short8*)&tA[(m * GX + (((k0 >> 3) | lq) ^ (m & 7))) * 8];
        }
#pragma unroll
        for (int ct = 0; ct < CT; ct++)
            b[ct] = *(const short8*)(Wp + (long long)(ct * 16 + lrow) * KX + k0 + lq * 8);
#pragma unroll
        for (int rt = 0; rt < 2; rt++)
#pragma unroll
            for (int ct = 0; ct < CT; ct++)
                acc[rt][ct] = __builtin_amdgcn_mfma_f32_16x16x32_bf16(a[rt], b[ct], acc[rt][ct], 0, 0, 0);
    }
#pragma unroll
    for (int ct = 0; ct < CT; ct++) {
        float s = 0.f, ss = 0.f;
#pragma unroll
        for (int rt = 0; rt < 2; rt++)
#pragma unroll
            for (int r = 0; r < 4; r++) { float v = acc[rt][ct][r]; s += v; ss += v * v; }
        s += __shfl_down(s, 32); ss += __shfl_down(ss, 32);
        s += __shfl_down(s, 16); ss += __shfl_down(ss, 16);
        if (lane < 16) {
            atomicAdd(&gsum[d * N + n0w + ct * 16 + lane], s);
            atomicAdd(&gssq[d * N + n0w + ct * 16 + lane], ss);
        }
    }
}

// ---------------------------------------------------------------------------
// Fused layer kernel, 256 threads (4 waves pure N-split), TM=32, 3 sequential
// GEMM phases (r0 structure). BN finalize + gate inlined in the epilogue.
template <int N, int KX, bool RESTAGE, bool FINAL>
__global__ __launch_bounds__(256, 2) void fused_k(
    const unsigned short* __restrict__ gin,
    const unsigned short* __restrict__ Xh,
    const unsigned short* __restrict__ W1,   // [d][N][256]
    const unsigned short* __restrict__ W2,   // [d][N][N]
    const unsigned short* __restrict__ Wm,   // [d][N][KX]
    const float* __restrict__ gb1, const float* __restrict__ gb2,
    const float* __restrict__ gsum, const float* __restrict__ gssq,
    const float* __restrict__ gma, const float* __restrict__ bta, float invB,
    unsigned short* __restrict__ Xn,
    const int* __restrict__ dom, const float* __restrict__ fw,
    const float* __restrict__ fb, float* __restrict__ outp) {
    constexpr int GG = N / 8;
    constexpr int GX = KX / 8;
    constexpr int NW = N / 4, CT = NW / 16;
    __shared__ __align__(16) unsigned short tA[TM * 256];  // gin (K=256), then Xh
    __shared__ __align__(16) unsigned short g1b[TM * N];
    const int t = threadIdx.x;
    const int d = blockIdx.y;
    const int m0 = blockIdx.x * TM;
    const int w = t >> 6, lane = t & 63, lrow = lane & 15, lq = lane >> 4;
    const int n0w = w * NW;

    {  // stage gin tile (K=256), XOR-swizzled granules
        const unsigned short* Gp = gin + (long long)m0 * 256;
#pragma unroll
        for (int r = 0; r < 4; r++) {
            int idx = r * 256 + t;
            int m = idx >> 5, j = idx & 31;
            uint4 v = *(const uint4*)(Gp + (long long)m * 256 + j * 8);
            *(uint4*)&tA[((m << 5) + (j ^ (m & 7))) * 8] = v;
        }
    }
    __syncthreads();

    // ---- phase g1: relu(gin @ W1 + b1) -> g1b (bf16, swizzled row-major)
    floatx4 acc1[2][CT];
#pragma unroll
    for (int rt = 0; rt < 2; rt++)
#pragma unroll
        for (int ct = 0; ct < CT; ct++) acc1[rt][ct] = (floatx4)(0.f);
    const unsigned short* W1p = W1 + ((long long)d * N + n0w) * 256;
#pragma unroll
    for (int k0 = 0; k0 < 256; k0 += 32) {
        short8 a[2], b[CT];
#pragma unroll
        for (int rt = 0; rt < 2; rt++) {
            int m = rt * 16 + lrow;
            a[rt] = *(const short8*)&tA[((m << 5) + (((k0 >> 3) | lq) ^ (m & 7))) * 8];
        }
#pragma unroll
        for (int ct = 0; ct < CT; ct++)
            b[ct] = *(const short8*)(W1p + (long long)(ct * 16 + lrow) * 256 + k0 + lq * 8);
#pragma unroll
        for (int rt = 0; rt < 2; rt++)
#pragma unroll
            for (int ct = 0; ct < CT; ct++)
                acc1[rt][ct] = __builtin_amdgcn_mfma_f32_16x16x32_bf16(a[rt], b[ct], acc1[rt][ct], 0, 0, 0);
    }
#pragma unroll
    for (int ct = 0; ct < CT; ct++) {
        int n = n0w + ct * 16 + lrow;
        float bs = gb1[d * N + n];
        int jj = n >> 3, sub = n & 7;
#pragma unroll
        for (int rt = 0; rt < 2; rt++)
#pragma unroll
            for (int r = 0; r < 4; r++) {
                int m = rt * 16 + lq * 4 + r;
                g1b[(m * GG + (jj ^ (m & 7))) * 8 + sub] = f2b(fmaxf(acc1[rt][ct][r] + bs, 0.f));
            }
    }
    __syncthreads();  // g1b writes -> g2 reads

    // ---- phase g2: acc2 = g1 @ W2 (gate finalized in epilogue)
    floatx4 acc2[2][CT];
#pragma unroll
    for (int rt = 0; rt < 2; rt++)
#pragma unroll
        for (int ct = 0; ct < CT; ct++) acc2[rt][ct] = (floatx4)(0.f);
    const unsigned short* W2p = W2 + ((long long)d * N + n0w) * N;
#pragma unroll
    for (int k0 = 0; k0 < N; k0 += 32) {
        short8 a[2], b[CT];
#pragma unroll
        for (int rt = 0; rt < 2; rt++) {
            int m = rt * 16 + lrow;
            a[rt] = *(const short8*)&g1b[(m * GG + (((k0 >> 3) | lq) ^ (m & 7))) * 8];
        }
#pragma unroll
        for (int ct = 0; ct < CT; ct++)
            b[ct] = *(const short8*)(W2p + (long long)(ct * 16 + lrow) * N + k0 + lq * 8);
#pragma unroll
        for (int rt = 0; rt < 2; rt++)
#pragma unroll
            for (int ct = 0; ct < CT; ct++)
                acc2[rt][ct] = __builtin_amdgcn_mfma_f32_16x16x32_bf16(a[rt], b[ct], acc2[rt][ct], 0, 0, 0);
    }

    if (RESTAGE) {  // overwrite tA with this layer's h-input
        const unsigned short* Xp = Xh + ((long long)d * BATCH + m0) * KX;
#pragma unroll
        for (int r = 0; r < TM * GX / 256; r++) {
            int idx = r * 256 + t;
            int m = idx / GX, j = idx % GX;
            uint4 v = *(const uint4*)(Xp + (long long)m * KX + j * 8);
            *(uint4*)&tA[(m * GX + (j ^ (m & 7))) * 8] = v;
        }
    }
    __syncthreads();  // restage done; also: everyone past g2 (g1b reusable)

    // ---- phase h: acch = X @ Wm (bias cancels in BN)
    floatx4 acch[2][CT];
#pragma unroll
    for (int rt = 0; rt < 2; rt++)
#pragma unroll
        for (int ct = 0; ct < CT; ct++) acch[rt][ct] = (floatx4)(0.f);
    const unsigned short* Wmp = Wm + ((long long)d * N + n0w) * KX;
#pragma unroll
    for (int k0 = 0; k0 < KX; k0 += 32) {
        short8 a[2], b[CT];
#pragma unroll
        for (int rt = 0; rt < 2; rt++) {
            int m = rt * 16 + lrow;
            a[rt] = *(const short8*)&tA[(m * GX + (((k0 >> 3) | lq) ^ (m & 7))) * 8];
        }
#pragma unroll
        for (int ct = 0; ct < CT; ct++)
            b[ct] = *(const short8*)(Wmp + (long long)(ct * 16 + lrow) * KX + k0 + lq * 8);
#pragma unroll
        for (int rt = 0; rt < 2; rt++)
#pragma unroll
            for (int ct = 0; ct < CT; ct++)
                acch[rt][ct] = __builtin_amdgcn_mfma_f32_16x16x32_bf16(a[rt], b[ct], acch[rt][ct], 0, 0, 0);
    }
    // ---- epilogue: BN finalize inline; X_next = relu(h*SC+SH)*gate -> g1b
#pragma unroll
    for (int ct = 0; ct < CT; ct++) {
        int n = n0w + ct * 16 + lrow;
        int i = d * N + n;
        float bs2 = gb2[i];
        float ma = gsum[i] * invB;
        float var = gssq[i] * invB - ma * ma;
        float sc = rsqrtf(var + 1e-5f) * gma[i];
        float sh = bta[i] - ma * sc;
        int jj = n >> 3, sub = n & 7;
#pragma unroll
        for (int rt = 0; rt < 2; rt++)
#pragma unroll
            for (int r = 0; r < 4; r++) {
                int m = rt * 16 + lq * 4 + r;
                float gate = 2.f / (1.f + __expf(-(acc2[rt][ct][r] + bs2)));
                float v = fmaxf(acch[rt][ct][r] * sc + sh, 0.f) * gate;
                g1b[(m * GG + (jj ^ (m & 7))) * 8 + sub] = f2b(v);
            }
    }
    __syncthreads();

    if (!FINAL) {
        unsigned short* Op = Xn + ((long long)d * BATCH + m0) * N;
#pragma unroll
        for (int r = 0; r < TM * GG / 256; r++) {
            int idx = r * 256 + t;
            int m = idx / GG, j = idx % GG;
            *(uint4*)(Op + (long long)m * N + j * 8) = *(const uint4*)&g1b[(m * GG + (j ^ (m & 7))) * 8];
        }
    } else {
        // final: out[b] = sigmoid(X3[b] . finW[d] + finb[d]) where d == dom[b]
        // TM=32 rows, 8 threads per row, 1 granule (8 elems) each (GG=8).
        int m = t >> 3, q = t & 7;
        const float* fwp = fw + d * 64;
        short8 v = *(const short8*)&g1b[(m * 8 + (q ^ (m & 7))) * 8];
        float s = 0.f;
#pragma unroll
        for (int kk = 0; kk < 8; kk++)
            s += b2f((unsigned short)v[kk]) * fwp[q * 8 + kk];
        s += __shfl_down(s, 4);
        s += __shfl_down(s, 2);
        s += __shfl_down(s, 1);
        if (q == 0) {
            int b = m0 + m;
            if (dom[b] == d) outp[b] = 1.f / (1.f + __expf(-(s + fb[d])));
        }
    }
}

// ---------------------------------------------------------------------------
extern "C" void kernel_launch(void* const* d_in, const int* in_sizes, int n_in,
                              void* d_out, int out_size, void* d_ws, size_t ws_size,
                              hipStream_t stream) {
    const int B = BATCH, D = NDOM;

    const int* id_idx = (const int*)d_in[0];
    const int* agn_idx = (const int*)d_in[1];
    const int* dom = (const int*)d_in[2];
    const float* id_t = (const float*)d_in[3];
    const float* agn_t = (const float*)d_in[4];
    const float *mlpW[3], *bng[3], *bnb[3], *gW1[3], *gb1[3], *gW2[3], *gb2[3];
    for (int i = 0; i < 3; i++) {
        int b0 = 5 + i * 8;
        mlpW[i] = (const float*)d_in[b0 + 0];
        bng[i] = (const float*)d_in[b0 + 2];
        bnb[i] = (const float*)d_in[b0 + 3];
        gW1[i] = (const float*)d_in[b0 + 4];
        gb1[i] = (const float*)d_in[b0 + 5];
        gW2[i] = (const float*)d_in[b0 + 6];
        gb2[i] = (const float*)d_in[b0 + 7];
    }
    const float* finW = (const float*)d_in[29];
    const float* finb = (const float*)d_in[30];

    char* wsc = (char*)d_ws;
    size_t off = 0;
    auto alloc = [&](size_t bytes) -> char* {
        char* p = wsc + off;
        off = (off + bytes + 255) & ~(size_t)255;
        return p;
    };

    struct { const float* src; int K, N; } mats[9] = {
        {mlpW[0], 256, 256}, {gW1[0], 256, 256}, {gW2[0], 256, 256},
        {mlpW[1], 256, 128}, {gW1[1], 256, 128}, {gW2[1], 128, 128},
        {mlpW[2], 128, 64},  {gW1[2], 256, 64},  {gW2[2], 64, 64}};
    unsigned pfx[10];
    pfx[0] = 0;
    for (int j = 0; j < 9; j++) pfx[j + 1] = pfx[j] + 4u * mats[j].K * mats[j].N;

    unsigned short* wt = (unsigned short*)alloc((size_t)pfx[9] * 2);
    unsigned short* gin = (unsigned short*)alloc((size_t)B * 256 * 2);
    float* stats = (float*)alloc((size_t)3 * 2 * D * 256 * 4);  // per layer: gsum, gssq
    unsigned short* X1 = (unsigned short*)alloc((size_t)D * B * 256 * 2);
    unsigned short* X2 = (unsigned short*)alloc((size_t)D * B * 128 * 2);

    PrepArgs pa;
    for (int j = 0; j < 9; j++) {
        pa.m[j].src = mats[j].src;
        pa.m[j].K = (unsigned)mats[j].K;
        pa.m[j].N = (unsigned)mats[j].N;
        pa.m[j].pfx = pfx[j];
        pa.m[j].total = 4u * mats[j].K * mats[j].N;
    }
    pa.stats = stats;
    pa.statsN = 3 * 2 * D * 256;
    pa.grand = pfx[9];

    const float invB = 1.f / (float)B;
    dim3 gs(B / TM, D);

    prep_k<<<dim3((pfx[9] + 255) / 256), 256, 0, stream>>>(pa, wt);
    embed_k<<<dim3(B * 16 / 256), 256, 0, stream>>>(id_idx, agn_idx, id_t, agn_t, gin);

    float* gsum0 = stats + 0 * 2 * D * 256; float* gssq0 = gsum0 + D * 256;
    float* gsum1 = stats + 1 * 2 * D * 256; float* gssq1 = gsum1 + D * 256;
    float* gsum2 = stats + 2 * 2 * D * 256; float* gssq2 = gsum2 + D * 256;

    // ---- layer 0 (K=256 -> N=256); h input == gin (no restage)
    stats_k<256, 256><<<gs, 256, 0, stream>>>(gin, 1, wt + pfx[0], gsum0, gssq0);
    fused_k<256, 256, false, false><<<gs, 256, 0, stream>>>(
        gin, gin, wt + pfx[1], wt + pfx[2], wt + pfx[0], gb1[0], gb2[0],
        gsum0, gssq0, bng[0], bnb[0], invB,
        X1, nullptr, nullptr, nullptr, nullptr);

    // ---- layer 1 (K=256 -> N=128)
    stats_k<128, 256><<<gs, 256, 0, stream>>>(X1, 0, wt + pfx[3], gsum1, gssq1);
    fused_k<128, 256, true, false><<<gs, 256, 0, stream>>>(
        gin, X1, wt + pfx[4], wt + pfx[5], wt + pfx[3], gb1[1], gb2[1],
        gsum1, gssq1, bng[1], bnb[1], invB,
        X2, nullptr, nullptr, nullptr, nullptr);

    // ---- layer 2 (K=128 -> N=64), with fused final dot + sigmoid + select
    stats_k<64, 128><<<gs, 256, 0, stream>>>(X2, 0, wt + pfx[6], gsum2, gssq2);
    fused_k<64, 128, true, true><<<gs, 256, 0, stream>>>(
        gin, X2, wt + pfx[7], wt + pfx[8], wt + pfx[6], gb1[2], gb2[2],
        gsum2, gssq2, bng[2], bnb[2], invB,
        nullptr, dom, finW, finb, (float*)d_out);
}

// Round 5
// 638.374 us; speedup vs baseline: 1.1602x; 1.1602x over previous
//
#include <hip/hip_runtime.h>

// PPNet forward, round 7: merged g1+h loop at TM=32 + LDS alias.
// Evidence ledger:
//  - r0 (TM=64, RT=4, 3 phases): 117us fused0, VGPR 124 no-spill, 16 MFMA/kstep.
//  - r2/r4: 8 MFMA/kstep halves MfmaUtil (18->9) even at HIGHER occupancy
//    => per-wave ILP per kstep dominates, not waves/CU.
//  - r3: merged g1+h at RT=4 needs ~210 VGPR -> spills at the ~128 boundary.
//  - r1/r2: __launch_bounds__ 2nd arg = min BLOCKS/CU (CUDA semantics).
// => Merged g1+h at TM=32/RT=2: 16 MFMA/kstep at ~120 VGPR (acc1 32 + acch 32
//    + aG 8 + b1 16 + bm 16). g1b overlays tG (tG dead after merged loop since
//    h runs inside it) -> fused LDS: l0 16KB, l1 32KB, l2 24KB -> 4+ blocks/CU.
//    stats_k reverted to the proven r0 TM=64 form.

typedef __attribute__((ext_vector_type(8))) short short8;
typedef __attribute__((ext_vector_type(4))) float floatx4;

#define BATCH 32768
#define NDOM 4
#define TMF 32  // fused tile rows
#define TMS 64  // stats tile rows

__device__ __forceinline__ unsigned short f2b(float f) {
    unsigned u = __float_as_uint(f);
    u += 0x7fffu + ((u >> 16) & 1u);  // round-to-nearest-even
    return (unsigned short)(u >> 16);
}
__device__ __forceinline__ float b2f(unsigned short h) {
    return __uint_as_float(((unsigned)h) << 16);
}

// ---------------------------------------------------------------------------
// Weight prep: fp32 (D,K,N) -> bf16 (D,N,K) packed; zero stat accumulators.
struct MatDesc { const float* src; unsigned K, N, pfx, total; };
struct PrepArgs { MatDesc m[9]; float* stats; unsigned statsN; unsigned grand; };

__global__ __launch_bounds__(256) void prep_k(PrepArgs a, unsigned short* __restrict__ wt) {
    unsigned e = blockIdx.x * 256 + threadIdx.x;
    if (e < a.statsN) a.stats[e] = 0.f;
    if (e >= a.grand) return;
    int j = 0;
    while (j < 8 && e >= a.m[j].pfx + a.m[j].total) j++;
    const unsigned K = a.m[j].K, N = a.m[j].N;
    const unsigned local = e - a.m[j].pfx;
    const unsigned kn = K * N;
    const unsigned d = local / kn;
    const unsigned r2 = local - d * kn;
    const unsigned n = r2 / K;
    const unsigned k = r2 - n * K;
    wt[e] = f2b(a.m[j].src[((long long)d * K + k) * N + n]);
}

// ---------------------------------------------------------------------------
__global__ __launch_bounds__(256) void embed_k(const int* __restrict__ idi, const int* __restrict__ agi,
                                               const float* __restrict__ idt, const float* __restrict__ agt,
                                               unsigned short* __restrict__ gin) {
    int t = blockIdx.x * 256 + threadIdx.x;  // B*16 threads, one per (b, 16-elem slot)
    int b = t >> 4, slot = t & 15;
    int f = slot & 7;
    const int* ip = (slot < 8) ? idi : agi;
    const float* tab = (slot < 8) ? idt : agt;
    int ix = ip[b * 8 + f];
    const float* src = tab + ((long long)f * 100000 + ix) * 16;
    unsigned short tmp[16];
#pragma unroll
    for (int j = 0; j < 16; j++) tmp[j] = f2b(src[j]);
    unsigned short* dst = gin + (long long)b * 256 + slot * 16;
    *(uint4*)dst = *(const uint4*)tmp;
    *(uint4*)(dst + 8) = *(const uint4*)(tmp + 8);
}

// ---------------------------------------------------------------------------
// Stats-only GEMM (r0-proven form): TM=64, 4 waves pure N-split, RT=4.
template <int N, int KX>
__global__ __launch_bounds__(256, 2) void stats_k(
    const unsigned short* __restrict__ X, int ginMode,
    const unsigned short* __restrict__ Wm,
    float* __restrict__ gsum, float* __restrict__ gssq) {
    constexpr int GX = KX / 8;
    constexpr int NW = N / 4, CT = NW / 16;
    __shared__ __align__(16) unsigned short tA[TMS * KX];
    const int t = threadIdx.x;
    const int d = blockIdx.y;
    const int m0 = blockIdx.x * TMS;
    const unsigned short* Xp = X + ((long long)(ginMode ? 0 : d * BATCH) + m0) * KX;
#pragma unroll
    for (int r = 0; r < TMS * GX / 256; r++) {
        int idx = r * 256 + t;
        int m = idx / GX, j = idx % GX;
        uint4 v = *(const uint4*)(Xp + (long long)m * KX + j * 8);
        *(uint4*)&tA[(m * GX + (j ^ (m & 7))) * 8] = v;
    }
    __syncthreads();
    const int w = t >> 6, lane = t & 63, lrow = lane & 15, lq = lane >> 4;
    const int n0w = w * NW;
    const unsigned short* Wp = Wm + ((long long)d * N + n0w) * KX;
    floatx4 acc[4][CT];
#pragma unroll
    for (int rt = 0; rt < 4; rt++)
#pragma unroll
        for (int ct = 0; ct < CT; ct++) acc[rt][ct] = (floatx4)(0.f);
#pragma unroll
    for (int k0 = 0; k0 < KX; k0 += 32) {
        short8 a[4], b[CT];
#pragma unroll
        for (int rt = 0; rt < 4; rt++) {
            int m = rt * 16 + lrow;
            a[rt] = *(const short8*)&tA[(m * GX + (((k0 >> 3) | lq) ^ (m & 7))) * 8];
        }
#pragma unroll
        for (int ct = 0; ct < CT; ct++)
            b[ct] = *(const short8*)(Wp + (long long)(ct * 16 + lrow) * KX + k0 + lq * 8);
#pragma unroll
        for (int rt = 0; rt < 4; rt++)
#pragma unroll
            for (int ct = 0; ct < CT; ct++)
                acc[rt][ct] = __builtin_amdgcn_mfma_f32_16x16x32_bf16(a[rt], b[ct], acc[rt][ct], 0, 0, 0);
    }
#pragma unroll
    for (int ct = 0; ct < CT; ct++) {
        float s = 0.f, ss = 0.f;
#pragma unroll
        for (int rt = 0; rt < 4; rt++)
#pragma unroll
            for (int r = 0; r < 4; r++) { float v = acc[rt][ct][r]; s += v; ss += v * v; }
        s += __shfl_down(s, 32); ss += __shfl_down(ss, 32);
        s += __shfl_down(s, 16); ss += __shfl_down(ss, 16);
        if (lane < 16) {
            atomicAdd(&gsum[d * N + n0w + ct * 16 + lane], s);
            atomicAdd(&gssq[d * N + n0w + ct * 16 + lane], ss);
        }
    }
}

// ---------------------------------------------------------------------------
// Fused layer kernel, 256 threads (4 waves pure N-split), TM=32, RT=2.
// Merged g1+h dual-accumulator k-loop (16 MFMA/kstep for layer 0); g1b LDS
// buffer overlays tG (dead after the merged loop). BN finalize + gate inlined.
template <int N, int KX, bool SHARED_A, bool FINAL>
__global__ __launch_bounds__(256, 2) void fused_k(
    const unsigned short* __restrict__ gin,
    const unsigned short* __restrict__ Xh,
    const unsigned short* __restrict__ W1,   // [d][N][256]
    const unsigned short* __restrict__ W2,   // [d][N][N]
    const unsigned short* __restrict__ Wm,   // [d][N][KX]
    const float* __restrict__ gb1, const float* __restrict__ gb2,
    const float* __restrict__ gsum, const float* __restrict__ gssq,
    const float* __restrict__ gma, const float* __restrict__ bta, float invB,
    unsigned short* __restrict__ Xn,
    const int* __restrict__ dom, const float* __restrict__ fw,
    const float* __restrict__ fb, float* __restrict__ outp) {
    constexpr int GG = N / 8;
    constexpr int GX = KX / 8;
    constexpr int NW = N / 4, CT = NW / 16;
    constexpr int TXN = SHARED_A ? 0 : TMF * KX;
    __shared__ __align__(16) unsigned short lds[TMF * 256 + TXN];
    unsigned short* tG = lds;                                   // gin tile (K=256)
    unsigned short* tX = SHARED_A ? lds : (lds + TMF * 256);    // Xh tile
    unsigned short* g1b = lds;                                  // overlays tG
    const int t = threadIdx.x;
    const int d = blockIdx.y;
    const int m0 = blockIdx.x * TMF;
    const int w = t >> 6, lane = t & 63, lrow = lane & 15, lq = lane >> 4;
    const int n0w = w * NW;

    {  // stage gin tile (K=256), XOR-swizzled granules
        const unsigned short* Gp = gin + (long long)m0 * 256;
#pragma unroll
        for (int r = 0; r < TMF * 32 / 256; r++) {
            int idx = r * 256 + t;
            int m = idx >> 5, j = idx & 31;
            uint4 v = *(const uint4*)(Gp + (long long)m * 256 + j * 8);
            *(uint4*)&tG[((m << 5) + (j ^ (m & 7))) * 8] = v;
        }
    }
    if constexpr (!SHARED_A) {  // stage Xh tile (K=KX)
        const unsigned short* Xp = Xh + ((long long)d * BATCH + m0) * KX;
#pragma unroll
        for (int r = 0; r < TMF * GX / 256; r++) {
            int idx = r * 256 + t;
            int m = idx / GX, j = idx % GX;
            uint4 v = *(const uint4*)(Xp + (long long)m * KX + j * 8);
            *(uint4*)&tX[(m * GX + (j ^ (m & 7))) * 8] = v;
        }
    }
    __syncthreads();

    // ---- merged phase: acc1 = gin@W1 and acch = X@Wm in one k-loop
    floatx4 acc1[2][CT], acch[2][CT];
#pragma unroll
    for (int rt = 0; rt < 2; rt++)
#pragma unroll
        for (int ct = 0; ct < CT; ct++) { acc1[rt][ct] = (floatx4)(0.f); acch[rt][ct] = (floatx4)(0.f); }
    const unsigned short* W1p = W1 + ((long long)d * N + n0w) * 256;
    const unsigned short* Wmp = Wm + ((long long)d * N + n0w) * KX;
#pragma unroll
    for (int k0 = 0; k0 < 256; k0 += 32) {
        short8 aG[2];
#pragma unroll
        for (int rt = 0; rt < 2; rt++) {
            int m = rt * 16 + lrow;
            aG[rt] = *(const short8*)&tG[((m << 5) + (((k0 >> 3) | lq) ^ (m & 7))) * 8];
        }
        short8 b1[CT];
#pragma unroll
        for (int ct = 0; ct < CT; ct++)
            b1[ct] = *(const short8*)(W1p + (long long)(ct * 16 + lrow) * 256 + k0 + lq * 8);
#pragma unroll
        for (int rt = 0; rt < 2; rt++)
#pragma unroll
            for (int ct = 0; ct < CT; ct++)
                acc1[rt][ct] = __builtin_amdgcn_mfma_f32_16x16x32_bf16(aG[rt], b1[ct], acc1[rt][ct], 0, 0, 0);
        if (k0 < KX) {  // h part (compile-time dead beyond KX)
            short8 aX[2], bm[CT];
            if constexpr (SHARED_A) {
#pragma unroll
                for (int rt = 0; rt < 2; rt++) aX[rt] = aG[rt];
            } else {
#pragma unroll
                for (int rt = 0; rt < 2; rt++) {
                    int m = rt * 16 + lrow;
                    aX[rt] = *(const short8*)&tX[(m * GX + (((k0 >> 3) | lq) ^ (m & 7))) * 8];
                }
            }
#pragma unroll
            for (int ct = 0; ct < CT; ct++)
                bm[ct] = *(const short8*)(Wmp + (long long)(ct * 16 + lrow) * KX + k0 + lq * 8);
#pragma unroll
            for (int rt = 0; rt < 2; rt++)
#pragma unroll
                for (int ct = 0; ct < CT; ct++)
                    acch[rt][ct] = __builtin_amdgcn_mfma_f32_16x16x32_bf16(aX[rt], bm[ct], acch[rt][ct], 0, 0, 0);
        }
    }
    __syncthreads();  // all tG/tX reads done; g1b (alias of tG) writes may begin

    // ---- g1 epilogue: relu(+b1) -> g1b (bf16, swizzled granules)
#pragma unroll
    for (int ct = 0; ct < CT; ct++) {
        int n = n0w + ct * 16 + lrow;
        float bs = gb1[d * N + n];
        int jj = n >> 3, sub = n & 7;
#pragma unroll
        for (int rt = 0; rt < 2; rt++)
#pragma unroll
            for (int r = 0; r < 4; r++) {
                int m = rt * 16 + lq * 4 + r;
                g1b[(m * GG + (jj ^ (m & 7))) * 8 + sub] = f2b(fmaxf(acc1[rt][ct][r] + bs, 0.f));
            }
    }
    __syncthreads();  // g1b writes -> g2 reads

    // ---- phase g2: acc2 = g1 @ W2 (acch parked in regs)
    floatx4 acc2[2][CT];
#pragma unroll
    for (int rt = 0; rt < 2; rt++)
#pragma unroll
        for (int ct = 0; ct < CT; ct++) acc2[rt][ct] = (floatx4)(0.f);
    const unsigned short* W2p = W2 + ((long long)d * N + n0w) * N;
#pragma unroll
    for (int k0 = 0; k0 < N; k0 += 32) {
        short8 a[2], b[CT];
#pragma unroll
        for (int rt = 0; rt < 2; rt++) {
            int m = rt * 16 + lrow;
            a[rt] = *(const short8*)&g1b[(m * GG + (((k0 >> 3) | lq) ^ (m & 7))) * 8];
        }
#pragma unroll
        for (int ct = 0; ct < CT; ct++)
            b[ct] = *(const short8*)(W2p + (long long)(ct * 16 + lrow) * N + k0 + lq * 8);
#pragma unroll
        for (int rt = 0; rt < 2; rt++)
#pragma unroll
            for (int ct = 0; ct < CT; ct++)
                acc2[rt][ct] = __builtin_amdgcn_mfma_f32_16x16x32_bf16(a[rt], b[ct], acc2[rt][ct], 0, 0, 0);
    }
    __syncthreads();  // g2 reads of g1b done before epilogue overwrites

    // ---- epilogue: BN finalize inline; X_next = relu(h*SC+SH)*gate -> g1b
#pragma unroll
    for (int ct = 0; ct < CT; ct++) {
        int n = n0w + ct * 16 + lrow;
        int i = d * N + n;
        float bs2 = gb2[i];
        float ma = gsum[i] * invB;
        float var = gssq[i] * invB - ma * ma;
        float sc = rsqrtf(var + 1e-5f) * gma[i];
        float sh = bta[i] - ma * sc;
        int jj = n >> 3, sub = n & 7;
#pragma unroll
        for (int rt = 0; rt < 2; rt++)
#pragma unroll
            for (int r = 0; r < 4; r++) {
                int m = rt * 16 + lq * 4 + r;
                float gate = 2.f / (1.f + __expf(-(acc2[rt][ct][r] + bs2)));
                float v = fmaxf(acch[rt][ct][r] * sc + sh, 0.f) * gate;
                g1b[(m * GG + (jj ^ (m & 7))) * 8 + sub] = f2b(v);
            }
    }
    __syncthreads();

    if (!FINAL) {
        unsigned short* Op = Xn + ((long long)d * BATCH + m0) * N;
#pragma unroll
        for (int r = 0; r < TMF * GG / 256; r++) {
            int idx = r * 256 + t;
            int m = idx / GG, j = idx % GG;
            *(uint4*)(Op + (long long)m * N + j * 8) = *(const uint4*)&g1b[(m * GG + (j ^ (m & 7))) * 8];
        }
    } else {
        // final: out[b] = sigmoid(X3[b] . finW[d] + finb[d]) where d == dom[b]
        // TMF=32 rows, 8 threads per row, 1 granule (8 elems) each (GG=8).
        int m = t >> 3, q = t & 7;
        const float* fwp = fw + d * 64;
        short8 v = *(const short8*)&g1b[(m * 8 + (q ^ (m & 7))) * 8];
        float s = 0.f;
#pragma unroll
        for (int kk = 0; kk < 8; kk++)
            s += b2f((unsigned short)v[kk]) * fwp[q * 8 + kk];
        s += __shfl_down(s, 4);
        s += __shfl_down(s, 2);
        s += __shfl_down(s, 1);
        if (q == 0) {
            int b = m0 + m;
            if (dom[b] == d) outp[b] = 1.f / (1.f + __expf(-(s + fb[d])));
        }
    }
}

// ---------------------------------------------------------------------------
extern "C" void kernel_launch(void* const* d_in, const int* in_sizes, int n_in,
                              void* d_out, int out_size, void* d_ws, size_t ws_size,
                              hipStream_t stream) {
    const int B = BATCH, D = NDOM;

    const int* id_idx = (const int*)d_in[0];
    const int* agn_idx = (const int*)d_in[1];
    const int* dom = (const int*)d_in[2];
    const float* id_t = (const float*)d_in[3];
    const float* agn_t = (const float*)d_in[4];
    const float *mlpW[3], *bng[3], *bnb[3], *gW1[3], *gb1[3], *gW2[3], *gb2[3];
    for (int i = 0; i < 3; i++) {
        int b0 = 5 + i * 8;
        mlpW[i] = (const float*)d_in[b0 + 0];
        bng[i] = (const float*)d_in[b0 + 2];
        bnb[i] = (const float*)d_in[b0 + 3];
        gW1[i] = (const float*)d_in[b0 + 4];
        gb1[i] = (const float*)d_in[b0 + 5];
        gW2[i] = (const float*)d_in[b0 + 6];
        gb2[i] = (const float*)d_in[b0 + 7];
    }
    const float* finW = (const float*)d_in[29];
    const float* finb = (const float*)d_in[30];

    char* wsc = (char*)d_ws;
    size_t off = 0;
    auto alloc = [&](size_t bytes) -> char* {
        char* p = wsc + off;
        off = (off + bytes + 255) & ~(size_t)255;
        return p;
    };

    struct { const float* src; int K, N; } mats[9] = {
        {mlpW[0], 256, 256}, {gW1[0], 256, 256}, {gW2[0], 256, 256},
        {mlpW[1], 256, 128}, {gW1[1], 256, 128}, {gW2[1], 128, 128},
        {mlpW[2], 128, 64},  {gW1[2], 256, 64},  {gW2[2], 64, 64}};
    unsigned pfx[10];
    pfx[0] = 0;
    for (int j = 0; j < 9; j++) pfx[j + 1] = pfx[j] + 4u * mats[j].K * mats[j].N;

    unsigned short* wt = (unsigned short*)alloc((size_t)pfx[9] * 2);
    unsigned short* gin = (unsigned short*)alloc((size_t)B * 256 * 2);
    float* stats = (float*)alloc((size_t)3 * 2 * D * 256 * 4);  // per layer: gsum, gssq
    unsigned short* X1 = (unsigned short*)alloc((size_t)D * B * 256 * 2);
    unsigned short* X2 = (unsigned short*)alloc((size_t)D * B * 128 * 2);

    PrepArgs pa;
    for (int j = 0; j < 9; j++) {
        pa.m[j].src = mats[j].src;
        pa.m[j].K = (unsigned)mats[j].K;
        pa.m[j].N = (unsigned)mats[j].N;
        pa.m[j].pfx = pfx[j];
        pa.m[j].total = 4u * mats[j].K * mats[j].N;
    }
    pa.stats = stats;
    pa.statsN = 3 * 2 * D * 256;
    pa.grand = pfx[9];

    const float invB = 1.f / (float)B;
    dim3 gs_s(B / TMS, D);
    dim3 gs_f(B / TMF, D);

    prep_k<<<dim3((pfx[9] + 255) / 256), 256, 0, stream>>>(pa, wt);
    embed_k<<<dim3(B * 16 / 256), 256, 0, stream>>>(id_idx, agn_idx, id_t, agn_t, gin);

    float* gsum0 = stats + 0 * 2 * D * 256; float* gssq0 = gsum0 + D * 256;
    float* gsum1 = stats + 1 * 2 * D * 256; float* gssq1 = gsum1 + D * 256;
    float* gsum2 = stats + 2 * 2 * D * 256; float* gssq2 = gsum2 + D * 256;

    // ---- layer 0 (K=256 -> N=256); h input == gin (SHARED_A)
    stats_k<256, 256><<<gs_s, 256, 0, stream>>>(gin, 1, wt + pfx[0], gsum0, gssq0);
    fused_k<256, 256, true, false><<<gs_f, 256, 0, stream>>>(
        gin, gin, wt + pfx[1], wt + pfx[2], wt + pfx[0], gb1[0], gb2[0],
        gsum0, gssq0, bng[0], bnb[0], invB,
        X1, nullptr, nullptr, nullptr, nullptr);

    // ---- layer 1 (K=256 -> N=128)
    stats_k<128, 256><<<gs_s, 256, 0, stream>>>(X1, 0, wt + pfx[3], gsum1, gssq1);
    fused_k<128, 256, false, false><<<gs_f, 256, 0, stream>>>(
        gin, X1, wt + pfx[4], wt + pfx[5], wt + pfx[3], gb1[1], gb2[1],
        gsum1, gssq1, bng[1], bnb[1], invB,
        X2, nullptr, nullptr, nullptr, nullptr);

    // ---- layer 2 (K=128 -> N=64), with fused final dot + sigmoid + select
    stats_k<64, 128><<<gs_s, 256, 0, stream>>>(X2, 0, wt + pfx[6], gsum2, gssq2);
    fused_k<64, 128, false, true><<<gs_f, 256, 0, stream>>>(
        gin, X2, wt + pfx[7], wt + pfx[8], wt + pfx[6], gb1[2], gb2[2],
        gsum2, gssq2, bng[2], bnb[2], invB,
        nullptr, dom, finW, finb, (float*)d_out);
}

// Round 7
// 470.436 us; speedup vs baseline: 1.5743x; 1.3570x over previous
//
#include <hip/hip_runtime.h>

// PPNet forward, round 9: r8 chain restructure, resubmitted with workspace fix.
// r8 failed with "container failed twice" — no counters. Audit found one fault
// candidate: ws usage grew to 130MB (h0 64 + h1 32 + h2 16 + gin 16 + wt 2.2)
// vs the 114MB peak of every passing round. If ws_size ~128MB, h2 ran OOB.
// Fix: h2 ALIASES h0's buffer (h0 dead after F0; h2 written in F1, read in F2).
// Peak back to the proven 114MB. Kernel code otherwise identical to r8:
//  - h computed ONCE per layer (103->81 GF, stats_k eliminated, 6->4 GEMM kernels)
//  - fused2_k: g1 -> g1b(LDS) -> g2 -> gate(regs) -> load h -> BN*gate in LDS
//    -> next-layer h GEMM + stats + store. Never two live 64-reg acc sets.
//  - one 32KB LDS buffer cycled gin -> g1b -> h/X -> h_next (r5-proven aliasing).

typedef __attribute__((ext_vector_type(8))) short short8;
typedef __attribute__((ext_vector_type(4))) float floatx4;

#define BATCH 32768
#define NDOM 4
#define TM 64

__device__ __forceinline__ unsigned short f2b(float f) {
    unsigned u = __float_as_uint(f);
    u += 0x7fffu + ((u >> 16) & 1u);  // round-to-nearest-even
    return (unsigned short)(u >> 16);
}
__device__ __forceinline__ float b2f(unsigned short h) {
    return __uint_as_float(((unsigned)h) << 16);
}

// ---------------------------------------------------------------------------
// Weight prep: fp32 (D,K,N) -> bf16 (D,N,K) packed; zero stat accumulators.
struct MatDesc { const float* src; unsigned K, N, pfx, total; };
struct PrepArgs { MatDesc m[9]; float* stats; unsigned statsN; unsigned grand; };

__global__ __launch_bounds__(256) void prep_k(PrepArgs a, unsigned short* __restrict__ wt) {
    unsigned e = blockIdx.x * 256 + threadIdx.x;
    if (e < a.statsN) a.stats[e] = 0.f;
    if (e >= a.grand) return;
    int j = 0;
    while (j < 8 && e >= a.m[j].pfx + a.m[j].total) j++;
    const unsigned K = a.m[j].K, N = a.m[j].N;
    const unsigned local = e - a.m[j].pfx;
    const unsigned kn = K * N;
    const unsigned d = local / kn;
    const unsigned r2 = local - d * kn;
    const unsigned n = r2 / K;
    const unsigned k = r2 - n * K;
    wt[e] = f2b(a.m[j].src[((long long)d * K + k) * N + n]);
}

// ---------------------------------------------------------------------------
__global__ __launch_bounds__(256) void embed_k(const int* __restrict__ idi, const int* __restrict__ agi,
                                               const float* __restrict__ idt, const float* __restrict__ agt,
                                               unsigned short* __restrict__ gin) {
    int t = blockIdx.x * 256 + threadIdx.x;  // B*16 threads, one per (b, 16-elem slot)
    int b = t >> 4, slot = t & 15;
    int f = slot & 7;
    const int* ip = (slot < 8) ? idi : agi;
    const float* tab = (slot < 8) ? idt : agt;
    int ix = ip[b * 8 + f];
    const float* src = tab + ((long long)f * 100000 + ix) * 16;
    unsigned short tmp[16];
#pragma unroll
    for (int j = 0; j < 16; j++) tmp[j] = f2b(src[j]);
    unsigned short* dst = gin + (long long)b * 256 + slot * 16;
    *(uint4*)dst = *(const uint4*)tmp;
    *(uint4*)(dst + 8) = *(const uint4*)(tmp + 8);
}

// ---------------------------------------------------------------------------
// h0_k: h0 = gin @ Wm0 (r0-proven GEMM shape), stats0 atomics, store h0 bf16.
__global__ __launch_bounds__(256, 2) void h0_k(
    const unsigned short* __restrict__ gin,
    const unsigned short* __restrict__ Wm,   // [d][256][256]
    float* __restrict__ gsum, float* __restrict__ gssq,
    unsigned short* __restrict__ hOut) {     // [d][B][256]
    __shared__ __align__(16) unsigned short tA[TM * 256];
    const int t = threadIdx.x;
    const int d = blockIdx.y;
    const int m0 = blockIdx.x * TM;
    const unsigned short* Xp = gin + (long long)m0 * 256;
#pragma unroll
    for (int r = 0; r < 8; r++) {
        int idx = r * 256 + t;
        int m = idx >> 5, j = idx & 31;
        uint4 v = *(const uint4*)(Xp + (long long)m * 256 + j * 8);
        *(uint4*)&tA[((m << 5) + (j ^ (m & 7))) * 8] = v;
    }
    __syncthreads();
    const int w = t >> 6, lane = t & 63, lrow = lane & 15, lq = lane >> 4;
    const int n0w = w * 64;
    const unsigned short* Wp = Wm + ((long long)d * 256 + n0w) * 256;
    floatx4 acc[4][4];
#pragma unroll
    for (int rt = 0; rt < 4; rt++)
#pragma unroll
        for (int ct = 0; ct < 4; ct++) acc[rt][ct] = (floatx4)(0.f);
#pragma unroll
    for (int k0 = 0; k0 < 256; k0 += 32) {
        short8 a[4], b[4];
#pragma unroll
        for (int rt = 0; rt < 4; rt++) {
            int m = rt * 16 + lrow;
            a[rt] = *(const short8*)&tA[((m << 5) + (((k0 >> 3) | lq) ^ (m & 7))) * 8];
        }
#pragma unroll
        for (int ct = 0; ct < 4; ct++)
            b[ct] = *(const short8*)(Wp + (long long)(ct * 16 + lrow) * 256 + k0 + lq * 8);
#pragma unroll
        for (int rt = 0; rt < 4; rt++)
#pragma unroll
            for (int ct = 0; ct < 4; ct++)
                acc[rt][ct] = __builtin_amdgcn_mfma_f32_16x16x32_bf16(a[rt], b[ct], acc[rt][ct], 0, 0, 0);
    }
    __syncthreads();  // tA dead; reuse for h staging
#pragma unroll
    for (int ct = 0; ct < 4; ct++) {
        float s = 0.f, ss = 0.f;
#pragma unroll
        for (int rt = 0; rt < 4; rt++)
#pragma unroll
            for (int r = 0; r < 4; r++) { float v = acc[rt][ct][r]; s += v; ss += v * v; }
        s += __shfl_down(s, 32); ss += __shfl_down(ss, 32);
        s += __shfl_down(s, 16); ss += __shfl_down(ss, 16);
        if (lane < 16) {
            atomicAdd(&gsum[d * 256 + n0w + ct * 16 + lane], s);
            atomicAdd(&gssq[d * 256 + n0w + ct * 16 + lane], ss);
        }
        int n = n0w + ct * 16 + lrow;
        int jj = n >> 3, sub = n & 7;
#pragma unroll
        for (int rt = 0; rt < 4; rt++)
#pragma unroll
            for (int r = 0; r < 4; r++) {
                int m = rt * 16 + lq * 4 + r;
                tA[((m << 5) + (jj ^ (m & 7))) * 8 + sub] = f2b(acc[rt][ct][r]);
            }
    }
    __syncthreads();
    unsigned short* Op = hOut + ((long long)d * BATCH + m0) * 256;
#pragma unroll
    for (int r = 0; r < 8; r++) {
        int idx = r * 256 + t;
        int m = idx >> 5, j = idx & 31;
        *(uint4*)(Op + (long long)m * 256 + j * 8) = *(const uint4*)&tA[((m << 5) + (j ^ (m & 7))) * 8];
    }
}

// ---------------------------------------------------------------------------
// fused2_k<N, NH, FINAL>: gate path for layer l (width N) + BN/gate epilogue on
// h_l (loaded from global) + next-layer h GEMM (K=N -> NH) with stats+store.
// One 32KB LDS buffer cycled: gin -> g1b -> h/X -> h_next.
template <int N, int NH, bool FINAL>
__global__ __launch_bounds__(256, 2) void fused2_k(
    const unsigned short* __restrict__ gin,
    const unsigned short* __restrict__ hIn,   // [d][B][N]
    const unsigned short* __restrict__ W1,    // [d][N][256]
    const unsigned short* __restrict__ W2,    // [d][N][N]
    const unsigned short* __restrict__ WmN,   // [d][NH][N]
    const float* __restrict__ gb1, const float* __restrict__ gb2,
    const float* __restrict__ gsum, const float* __restrict__ gssq,
    const float* __restrict__ gma, const float* __restrict__ bta, float invB,
    unsigned short* __restrict__ hNext,       // [d][B][NH]
    float* __restrict__ gsumN, float* __restrict__ gssqN,
    const int* __restrict__ dom, const float* __restrict__ fw,
    const float* __restrict__ fb, float* __restrict__ outp) {
    constexpr int GG = N / 8;
    constexpr int NW = N / 4, CT = NW / 16;
    constexpr int NWH = NH / 4, CTH = NH / 64;
    constexpr int GH = NH / 8;
    __shared__ __align__(16) unsigned short buf[TM * 256];
    const int t = threadIdx.x;
    const int d = blockIdx.y;
    const int m0 = blockIdx.x * TM;
    const int w = t >> 6, lane = t & 63, lrow = lane & 15, lq = lane >> 4;
    const int n0w = w * NW;

    {  // stage gin tile (TM x 256), XOR-swizzled granules
        const unsigned short* Gp = gin + (long long)m0 * 256;
#pragma unroll
        for (int r = 0; r < 8; r++) {
            int idx = r * 256 + t;
            int m = idx >> 5, j = idx & 31;
            uint4 v = *(const uint4*)(Gp + (long long)m * 256 + j * 8);
            *(uint4*)&buf[((m << 5) + (j ^ (m & 7))) * 8] = v;
        }
    }
    __syncthreads();

    // ---- phase g1: acc1 = gin @ W1 (K=256)
    floatx4 acc1[4][CT];
#pragma unroll
    for (int rt = 0; rt < 4; rt++)
#pragma unroll
        for (int ct = 0; ct < CT; ct++) acc1[rt][ct] = (floatx4)(0.f);
    const unsigned short* W1p = W1 + ((long long)d * N + n0w) * 256;
#pragma unroll
    for (int k0 = 0; k0 < 256; k0 += 32) {
        short8 a[4], b[CT];
#pragma unroll
        for (int rt = 0; rt < 4; rt++) {
            int m = rt * 16 + lrow;
            a[rt] = *(const short8*)&buf[((m << 5) + (((k0 >> 3) | lq) ^ (m & 7))) * 8];
        }
#pragma unroll
        for (int ct = 0; ct < CT; ct++)
            b[ct] = *(const short8*)(W1p + (long long)(ct * 16 + lrow) * 256 + k0 + lq * 8);
#pragma unroll
        for (int rt = 0; rt < 4; rt++)
#pragma unroll
            for (int ct = 0; ct < CT; ct++)
                acc1[rt][ct] = __builtin_amdgcn_mfma_f32_16x16x32_bf16(a[rt], b[ct], acc1[rt][ct], 0, 0, 0);
    }
    __syncthreads();  // gin dead; buf becomes g1b

    // g1 epilogue: relu(+b1) -> buf (bf16, swizzled granules, GG per row)
#pragma unroll
    for (int ct = 0; ct < CT; ct++) {
        int n = n0w + ct * 16 + lrow;
        float bs = gb1[d * N + n];
        int jj = n >> 3, sub = n & 7;
#pragma unroll
        for (int rt = 0; rt < 4; rt++)
#pragma unroll
            for (int r = 0; r < 4; r++) {
                int m = rt * 16 + lq * 4 + r;
                buf[(m * GG + (jj ^ (m & 7))) * 8 + sub] = f2b(fmaxf(acc1[rt][ct][r] + bs, 0.f));
            }
    }
    __syncthreads();

    // ---- phase g2: acc2 = g1 @ W2 (K=N), gate -> regs
    floatx4 acc2[4][CT];
#pragma unroll
    for (int rt = 0; rt < 4; rt++)
#pragma unroll
        for (int ct = 0; ct < CT; ct++) acc2[rt][ct] = (floatx4)(0.f);
    const unsigned short* W2p = W2 + ((long long)d * N + n0w) * N;
#pragma unroll
    for (int k0 = 0; k0 < N; k0 += 32) {
        short8 a[4], b[CT];
#pragma unroll
        for (int rt = 0; rt < 4; rt++) {
            int m = rt * 16 + lrow;
            a[rt] = *(const short8*)&buf[(m * GG + (((k0 >> 3) | lq) ^ (m & 7))) * 8];
        }
#pragma unroll
        for (int ct = 0; ct < CT; ct++)
            b[ct] = *(const short8*)(W2p + (long long)(ct * 16 + lrow) * N + k0 + lq * 8);
#pragma unroll
        for (int rt = 0; rt < 4; rt++)
#pragma unroll
            for (int ct = 0; ct < CT; ct++)
                acc2[rt][ct] = __builtin_amdgcn_mfma_f32_16x16x32_bf16(a[rt], b[ct], acc2[rt][ct], 0, 0, 0);
    }
    float gate[4][CT][4];
#pragma unroll
    for (int ct = 0; ct < CT; ct++) {
        float bs2 = gb2[d * N + n0w + ct * 16 + lrow];
#pragma unroll
        for (int rt = 0; rt < 4; rt++)
#pragma unroll
            for (int r = 0; r < 4; r++)
                gate[rt][ct][r] = 2.f / (1.f + __expf(-(acc2[rt][ct][r] + bs2)));
    }
    __syncthreads();  // g1b dead; buf becomes h tile

    {  // stage h_l tile (TM x N), swizzled granules
        const unsigned short* Hp = hIn + ((long long)d * BATCH + m0) * N;
#pragma unroll
        for (int r = 0; r < TM * GG / 256; r++) {
            int idx = r * 256 + t;
            int m = idx / GG, j = idx % GG;
            uint4 v = *(const uint4*)(Hp + (long long)m * N + j * 8);
            *(uint4*)&buf[(m * GG + (j ^ (m & 7))) * 8] = v;
        }
    }
    __syncthreads();

    // ---- epilogue in-place: X = relu(BN(h)) * gate (per-thread disjoint elems)
#pragma unroll
    for (int ct = 0; ct < CT; ct++) {
        int n = n0w + ct * 16 + lrow;
        int i = d * N + n;
        float ma = gsum[i] * invB;
        float var = gssq[i] * invB - ma * ma;
        float sc = rsqrtf(var + 1e-5f) * gma[i];
        float sh = bta[i] - ma * sc;
        int jj = n >> 3, sub = n & 7;
#pragma unroll
        for (int rt = 0; rt < 4; rt++)
#pragma unroll
            for (int r = 0; r < 4; r++) {
                int m = rt * 16 + lq * 4 + r;
                int idx = (m * GG + (jj ^ (m & 7))) * 8 + sub;
                float hv = b2f(buf[idx]);
                buf[idx] = f2b(fmaxf(hv * sc + sh, 0.f) * gate[rt][ct][r]);
            }
    }
    __syncthreads();

    if constexpr (!FINAL) {
        // ---- next-layer h GEMM: acch = X @ WmN (K=N -> NH), stats + store
        const int n0h = w * NWH;
        floatx4 acch[4][CTH];
#pragma unroll
        for (int rt = 0; rt < 4; rt++)
#pragma unroll
            for (int ct = 0; ct < CTH; ct++) acch[rt][ct] = (floatx4)(0.f);
        const unsigned short* Wp = WmN + ((long long)d * NH + n0h) * N;
#pragma unroll
        for (int k0 = 0; k0 < N; k0 += 32) {
            short8 a[4], b[CTH];
#pragma unroll
            for (int rt = 0; rt < 4; rt++) {
                int m = rt * 16 + lrow;
                a[rt] = *(const short8*)&buf[(m * GG + (((k0 >> 3) | lq) ^ (m & 7))) * 8];
            }
#pragma unroll
            for (int ct = 0; ct < CTH; ct++)
                b[ct] = *(const short8*)(Wp + (long long)(ct * 16 + lrow) * N + k0 + lq * 8);
#pragma unroll
            for (int rt = 0; rt < 4; rt++)
#pragma unroll
                for (int ct = 0; ct < CTH; ct++)
                    acch[rt][ct] = __builtin_amdgcn_mfma_f32_16x16x32_bf16(a[rt], b[ct], acch[rt][ct], 0, 0, 0);
        }
        __syncthreads();  // X dead; buf becomes h_next staging
#pragma unroll
        for (int ct = 0; ct < CTH; ct++) {
            float s = 0.f, ss = 0.f;
#pragma unroll
            for (int rt = 0; rt < 4; rt++)
#pragma unroll
                for (int r = 0; r < 4; r++) { float v = acch[rt][ct][r]; s += v; ss += v * v; }
            s += __shfl_down(s, 32); ss += __shfl_down(ss, 32);
            s += __shfl_down(s, 16); ss += __shfl_down(ss, 16);
            if (lane < 16) {
                atomicAdd(&gsumN[d * NH + n0h + ct * 16 + lane], s);
                atomicAdd(&gssqN[d * NH + n0h + ct * 16 + lane], ss);
            }
            int n = n0h + ct * 16 + lrow;
            int jj = n >> 3, sub = n & 7;
#pragma unroll
            for (int rt = 0; rt < 4; rt++)
#pragma unroll
                for (int r = 0; r < 4; r++) {
                    int m = rt * 16 + lq * 4 + r;
                    buf[(m * GH + (jj ^ (m & 7))) * 8 + sub] = f2b(acch[rt][ct][r]);
                }
        }
        __syncthreads();
        unsigned short* Op = hNext + ((long long)d * BATCH + m0) * NH;
#pragma unroll
        for (int r = 0; r < TM * GH / 256; r++) {
            int idx = r * 256 + t;
            int m = idx / GH, j = idx % GH;
            *(uint4*)(Op + (long long)m * NH + j * 8) = *(const uint4*)&buf[(m * GH + (j ^ (m & 7))) * 8];
        }
    } else {
        // final: out[b] = sigmoid(X3[b] . finW[d] + finb[d]) where d == dom[b]
        // X3 in buf, TM=64 rows x 64 cols swizzled (GG=8); 4 threads/row.
        int m = t >> 2, q = t & 3;
        const float* fwp = fw + d * 64;
        float s = 0.f;
#pragma unroll
        for (int g = 0; g < 2; g++) {
            int j = q * 2 + g;
            short8 v = *(const short8*)&buf[(m * 8 + (j ^ (m & 7))) * 8];
#pragma unroll
            for (int kk = 0; kk < 8; kk++)
                s += b2f((unsigned short)v[kk]) * fwp[j * 8 + kk];
        }
        s += __shfl_down(s, 1);
        s += __shfl_down(s, 2);
        if (q == 0) {
            int b = m0 + m;
            if (dom[b] == d) outp[b] = 1.f / (1.f + __expf(-(s + fb[d])));
        }
    }
}

// ---------------------------------------------------------------------------
extern "C" void kernel_launch(void* const* d_in, const int* in_sizes, int n_in,
                              void* d_out, int out_size, void* d_ws, size_t ws_size,
                              hipStream_t stream) {
    const int B = BATCH, D = NDOM;

    const int* id_idx = (const int*)d_in[0];
    const int* agn_idx = (const int*)d_in[1];
    const int* dom = (const int*)d_in[2];
    const float* id_t = (const float*)d_in[3];
    const float* agn_t = (const float*)d_in[4];
    const float *mlpW[3], *bng[3], *bnb[3], *gW1[3], *gb1[3], *gW2[3], *gb2[3];
    for (int i = 0; i < 3; i++) {
        int b0 = 5 + i * 8;
        mlpW[i] = (const float*)d_in[b0 + 0];
        bng[i] = (const float*)d_in[b0 + 2];
        bnb[i] = (const float*)d_in[b0 + 3];
        gW1[i] = (const float*)d_in[b0 + 4];
        gb1[i] = (const float*)d_in[b0 + 5];
        gW2[i] = (const float*)d_in[b0 + 6];
        gb2[i] = (const float*)d_in[b0 + 7];
    }
    const float* finW = (const float*)d_in[29];
    const float* finb = (const float*)d_in[30];

    char* wsc = (char*)d_ws;
    size_t off = 0;
    auto alloc = [&](size_t bytes) -> char* {
        char* p = wsc + off;
        off = (off + bytes + 255) & ~(size_t)255;
        return p;
    };

    struct { const float* src; int K, N; } mats[9] = {
        {mlpW[0], 256, 256}, {gW1[0], 256, 256}, {gW2[0], 256, 256},
        {mlpW[1], 256, 128}, {gW1[1], 256, 128}, {gW2[1], 128, 128},
        {mlpW[2], 128, 64},  {gW1[2], 256, 64},  {gW2[2], 64, 64}};
    unsigned pfx[10];
    pfx[0] = 0;
    for (int j = 0; j < 9; j++) pfx[j + 1] = pfx[j] + 4u * mats[j].K * mats[j].N;

    unsigned short* wt = (unsigned short*)alloc((size_t)pfx[9] * 2);
    unsigned short* gin = (unsigned short*)alloc((size_t)B * 256 * 2);
    float* stats = (float*)alloc((size_t)3 * 2 * D * 256 * 4);  // per layer: gsum, gssq
    unsigned short* h0 = (unsigned short*)alloc((size_t)D * B * 256 * 2);
    unsigned short* h1 = (unsigned short*)alloc((size_t)D * B * 128 * 2);
    unsigned short* h2 = h0;  // ALIAS: h0 dead after F0 reads it; h2 written in F1.

    PrepArgs pa;
    for (int j = 0; j < 9; j++) {
        pa.m[j].src = mats[j].src;
        pa.m[j].K = (unsigned)mats[j].K;
        pa.m[j].N = (unsigned)mats[j].N;
        pa.m[j].pfx = pfx[j];
        pa.m[j].total = 4u * mats[j].K * mats[j].N;
    }
    pa.stats = stats;
    pa.statsN = 3 * 2 * D * 256;
    pa.grand = pfx[9];

    const float invB = 1.f / (float)B;
    dim3 gs(B / TM, D);

    prep_k<<<dim3((pfx[9] + 255) / 256), 256, 0, stream>>>(pa, wt);
    embed_k<<<dim3(B * 16 / 256), 256, 0, stream>>>(id_idx, agn_idx, id_t, agn_t, gin);

    float* gsum0 = stats + 0 * 2 * D * 256; float* gssq0 = gsum0 + D * 256;
    float* gsum1 = stats + 1 * 2 * D * 256; float* gssq1 = gsum1 + D * 256;
    float* gsum2 = stats + 2 * 2 * D * 256; float* gssq2 = gsum2 + D * 256;

    // h0 = gin @ Wm0, stats0, store
    h0_k<<<gs, 256, 0, stream>>>(gin, wt + pfx[0], gsum0, gssq0, h0);

    // F0: gate0 + BN(h0)*gate -> X1 (LDS) -> h1 = X1 @ Wm1, stats1, store
    fused2_k<256, 128, false><<<gs, 256, 0, stream>>>(
        gin, h0, wt + pfx[1], wt + pfx[2], wt + pfx[3], gb1[0], gb2[0],
        gsum0, gssq0, bng[0], bnb[0], invB,
        h1, gsum1, gssq1, nullptr, nullptr, nullptr, nullptr);

    // F1: gate1 + BN(h1)*gate -> X2 -> h2 = X2 @ Wm2, stats2, store (h2 aliases h0)
    fused2_k<128, 64, false><<<gs, 256, 0, stream>>>(
        gin, h1, wt + pfx[4], wt + pfx[5], wt + pfx[6], gb1[1], gb2[1],
        gsum1, gssq1, bng[1], bnb[1], invB,
        h2, gsum2, gssq2, nullptr, nullptr, nullptr, nullptr);

    // F2: gate2 + BN(h2)*gate -> X3 -> final dot + sigmoid + domain select
    fused2_k<64, 64, true><<<gs, 256, 0, stream>>>(
        gin, h2, wt + pfx[7], wt + pfx[8], nullptr, gb1[2], gb2[2],
        gsum2, gssq2, bng[2], bnb[2], invB,
        nullptr, nullptr, nullptr, dom, finW, finb, (float*)d_out);
}